// Round 8
// baseline (338.164 us; speedup 1.0000x reference)
//
#include <hip/hip_runtime.h>
#include <stdint.h>

#define N_NODES 100000
#define N_EDGES 1000000
#define NB 782  // ceil(N_NODES/128) buckets of 128 nodes

typedef __attribute__((ext_vector_type(2))) _Float16 f16x2;
typedef __attribute__((ext_vector_type(8))) _Float16 f16x8;
typedef __attribute__((ext_vector_type(4))) float f32x4;

__device__ __forceinline__ unsigned short f2h(float f) {
  _Float16 h = (_Float16)f;
  return *(unsigned short*)&h;
}

// ---------------- bucketed CSR build ----------------

__global__ void k_hist(const int* __restrict__ dst, int* __restrict__ bcount) {
  __shared__ int h[NB];
  int t = threadIdx.x;
  for (int i = t; i < NB; i += 256) h[i] = 0;
  __syncthreads();
  int base = blockIdx.x * 4096;
#pragma unroll
  for (int k = 0; k < 16; k++) {
    int i = base + t + k * 256;
    if (i < N_EDGES) atomicAdd(&h[dst[i] >> 7], 1);
  }
  __syncthreads();
  for (int i = t; i < NB; i += 256)
    if (h[i]) atomicAdd(&bcount[i], h[i]);
}

__global__ __launch_bounds__(1024) void k_bscan(const int* __restrict__ bcount,
                                                int* __restrict__ boff,
                                                int* __restrict__ bcursor) {
  __shared__ int sc[1024];
  int t = threadIdx.x;
  int v = (t < NB) ? bcount[t] : 0;
  sc[t] = v;
  __syncthreads();
  for (int off = 1; off < 1024; off <<= 1) {
    int a = (t >= off) ? sc[t - off] : 0;
    __syncthreads();
    sc[t] += a;
    __syncthreads();
  }
  if (t < NB) {
    boff[t + 1] = sc[t];
    bcursor[t] = sc[t] - v;
  }
  if (t == 0) boff[0] = 0;
}

#define EPB 4096  // edges per scatter block -> 245 workgroups
__global__ void k_scatter(const int* __restrict__ src, const int* __restrict__ dst,
                          int* __restrict__ bcursor, unsigned int* __restrict__ stage) {
  __shared__ int h[NB];
  __shared__ int cur[NB];
  int t = threadIdx.x;
  for (int i = t; i < NB; i += 256) h[i] = 0;
  __syncthreads();
  int base = blockIdx.x * EPB;
#pragma unroll 4
  for (int k = 0; k < EPB / 256; k++) {
    int i = base + t + k * 256;
    if (i < N_EDGES) atomicAdd(&h[dst[i] >> 7], 1);
  }
  __syncthreads();
  for (int i = t; i < NB; i += 256) {
    int c = h[i];
    cur[i] = c ? atomicAdd(&bcursor[i], c) : 0;
  }
  __syncthreads();
#pragma unroll 4
  for (int k = 0; k < EPB / 256; k++) {
    int i = base + t + k * 256;
    if (i < N_EDGES) {
      int d = dst[i];
      int b = d >> 7;
      int pos = atomicAdd(&cur[b], 1);
      stage[pos] = ((unsigned int)(d & 127) << 17) | (unsigned int)src[i];
    }
  }
}

__global__ void k_bucket(const unsigned int* __restrict__ stage, const int* __restrict__ boff,
                         int* __restrict__ csr, int* __restrict__ row_off,
                         float* __restrict__ dinv) {
  __shared__ int cnt[128], sc[128], cur[128];
  int b = blockIdx.x, t = threadIdx.x;
  int e0 = boff[b], e1 = boff[b + 1];
  if (t < 128) cnt[t] = 0;
  __syncthreads();
  for (int e = e0 + t; e < e1; e += 256)
    atomicAdd(&cnt[stage[e] >> 17], 1);
  __syncthreads();
  int myc = (t < 128) ? cnt[t] : 0;
  if (t < 128) sc[t] = myc;
  __syncthreads();
  for (int off = 1; off < 128; off <<= 1) {
    int a = (t < 128 && t >= off) ? sc[t - off] : 0;
    __syncthreads();
    if (t < 128) sc[t] += a;
    __syncthreads();
  }
  if (t < 128) {
    int node = b * 128 + t;
    int ex = sc[t] - myc;
    cur[t] = ex;
    if (node < N_NODES) {
      row_off[node] = e0 + ex;
      dinv[node] = myc ? 1.0f / (float)myc : 0.0f;
    }
  }
  if (b == NB - 1 && t == 0) row_off[N_NODES] = N_EDGES;
  __syncthreads();
  for (int e = e0 + t; e < e1; e += 256) {
    unsigned int v = stage[e];
    int l = v >> 17;
    int pos = e0 + atomicAdd(&cur[l], 1);
    csr[pos] = (int)(v & 0x1FFFFu);
  }
}

// ---------------- fp32 -> f16 cast (x) ----------------
__global__ void k_cast(const float* __restrict__ x, unsigned short* __restrict__ xb) {
  int i = blockIdx.x * 256 + threadIdx.x;
  if (i >= N_NODES * 16) return;
  float4 a = ((const float4*)x)[2 * i];
  float4 b = ((const float4*)x)[2 * i + 1];
  unsigned short r[8] = {f2h(a.x), f2h(a.y), f2h(a.z), f2h(a.w),
                         f2h(b.x), f2h(b.y), f2h(b.z), f2h(b.w)};
  *(uint4*)(xb + (size_t)i * 8) = *(uint4*)r;
}

// ---------------- weight prep: f16, transposed + K-concat ----------------
__global__ void k_wprep(const float* __restrict__ WS, const float* __restrict__ WN,
                        int nout, unsigned short* __restrict__ wt) {
  int t = blockIdx.x * 256 + threadIdx.x;
  if (t >= nout * 128) return;
  int n = t >> 7, k = t & 127;
  wt[n * 256 + k] = f2h(WS[(size_t)k * nout + n]);
  wt[n * 256 + 128 + k] = f2h(WN[(size_t)k * nout + n]);
}

// ---------------- aggregation: persistent waves, 2 nodes/wave in flight ----------------
// grid 3125 blocks * 4 waves = 12500 waves; 12500*2*4 == 100000 (zero tail)
#define AGG_BLOCKS 3125
__global__ __launch_bounds__(256) void k_agg(
    const unsigned short* __restrict__ feat, const int* __restrict__ row_off,
    const int* __restrict__ csr, const float* __restrict__ dinv,
    unsigned short* __restrict__ nm) {
  const uint4* fp = (const uint4*)feat;  // 16 uint4 per feature row
  int wid = (blockIdx.x * 256 + threadIdx.x) >> 6;
  int lane = threadIdx.x & 63;
  int g = lane >> 4, c = lane & 15;
  const int STRIDE = AGG_BLOCKS * 4 * 2;
  for (int n0 = wid * 2; n0 < N_NODES; n0 += STRIDE) {
    int sa = row_off[n0];
    int mm = row_off[n0 + 1];
    int ee = row_off[n0 + 2];  // n0+1 < N_NODES always (N even), so valid
    f16x2 p0 = {0, 0}, p1 = {0, 0}, p2 = {0, 0}, p3 = {0, 0};
    f16x2 q0 = {0, 0}, q1 = {0, 0}, q2 = {0, 0}, q3 = {0, 0};
    int j0 = sa + g, j1 = mm + g;
    while (j0 < mm || j1 < ee) {
      int a1 = j0 + 4, a2 = j0 + 8, a3 = j0 + 12;
      int b1 = j1 + 4, b2 = j1 + 8, b3 = j1 + 12;
      bool ha0 = j0 < mm, ha1 = a1 < mm, ha2 = a2 < mm, ha3 = a3 < mm;
      bool hb0 = j1 < ee, hb1 = b1 < ee, hb2 = b2 < ee, hb3 = b3 < ee;
      // all 8 index loads first
      int ca0 = ha0 ? csr[j0] : 0;
      int ca1 = ha1 ? csr[a1] : 0;
      int ca2 = ha2 ? csr[a2] : 0;
      int ca3 = ha3 ? csr[a3] : 0;
      int cb0 = hb0 ? csr[j1] : 0;
      int cb1 = hb1 ? csr[b1] : 0;
      int cb2 = hb2 ? csr[b2] : 0;
      int cb3 = hb3 ? csr[b3] : 0;
      // then all 8 row gathers
      uint4 va0, va1, va2, va3, vb0, vb1, vb2, vb3;
      if (ha0) va0 = fp[(size_t)ca0 * 16 + c];
      if (ha1) va1 = fp[(size_t)ca1 * 16 + c];
      if (ha2) va2 = fp[(size_t)ca2 * 16 + c];
      if (ha3) va3 = fp[(size_t)ca3 * 16 + c];
      if (hb0) vb0 = fp[(size_t)cb0 * 16 + c];
      if (hb1) vb1 = fp[(size_t)cb1 * 16 + c];
      if (hb2) vb2 = fp[(size_t)cb2 * 16 + c];
      if (hb3) vb3 = fp[(size_t)cb3 * 16 + c];
      if (ha0) {
        p0 += *(const f16x2*)&va0.x; p1 += *(const f16x2*)&va0.y;
        p2 += *(const f16x2*)&va0.z; p3 += *(const f16x2*)&va0.w;
      }
      if (ha1) {
        p0 += *(const f16x2*)&va1.x; p1 += *(const f16x2*)&va1.y;
        p2 += *(const f16x2*)&va1.z; p3 += *(const f16x2*)&va1.w;
      }
      if (ha2) {
        p0 += *(const f16x2*)&va2.x; p1 += *(const f16x2*)&va2.y;
        p2 += *(const f16x2*)&va2.z; p3 += *(const f16x2*)&va2.w;
      }
      if (ha3) {
        p0 += *(const f16x2*)&va3.x; p1 += *(const f16x2*)&va3.y;
        p2 += *(const f16x2*)&va3.z; p3 += *(const f16x2*)&va3.w;
      }
      if (hb0) {
        q0 += *(const f16x2*)&vb0.x; q1 += *(const f16x2*)&vb0.y;
        q2 += *(const f16x2*)&vb0.z; q3 += *(const f16x2*)&vb0.w;
      }
      if (hb1) {
        q0 += *(const f16x2*)&vb1.x; q1 += *(const f16x2*)&vb1.y;
        q2 += *(const f16x2*)&vb1.z; q3 += *(const f16x2*)&vb1.w;
      }
      if (hb2) {
        q0 += *(const f16x2*)&vb2.x; q1 += *(const f16x2*)&vb2.y;
        q2 += *(const f16x2*)&vb2.z; q3 += *(const f16x2*)&vb2.w;
      }
      if (hb3) {
        q0 += *(const f16x2*)&vb3.x; q1 += *(const f16x2*)&vb3.y;
        q2 += *(const f16x2*)&vb3.z; q3 += *(const f16x2*)&vb3.w;
      }
      j0 += 16; j1 += 16;
    }
    float x0 = (float)p0[0], x1 = (float)p0[1], x2 = (float)p1[0], x3 = (float)p1[1];
    float x4 = (float)p2[0], x5 = (float)p2[1], x6 = (float)p3[0], x7 = (float)p3[1];
    float y0 = (float)q0[0], y1 = (float)q0[1], y2 = (float)q1[0], y3 = (float)q1[1];
    float y4 = (float)q2[0], y5 = (float)q2[1], y6 = (float)q3[0], y7 = (float)q3[1];
#define RED(x) x += __shfl_xor(x, 16); x += __shfl_xor(x, 32);
    RED(x0) RED(x1) RED(x2) RED(x3) RED(x4) RED(x5) RED(x6) RED(x7)
    RED(y0) RED(y1) RED(y2) RED(y3) RED(y4) RED(y5) RED(y6) RED(y7)
#undef RED
    if (g == 0) {
      float di = dinv[n0];
      uint4 o;
      o.x = ((unsigned int)f2h(x1 * di) << 16) | (unsigned int)f2h(x0 * di);
      o.y = ((unsigned int)f2h(x3 * di) << 16) | (unsigned int)f2h(x2 * di);
      o.z = ((unsigned int)f2h(x5 * di) << 16) | (unsigned int)f2h(x4 * di);
      o.w = ((unsigned int)f2h(x7 * di) << 16) | (unsigned int)f2h(x6 * di);
      ((uint4*)(nm + (size_t)n0 * 128))[c] = o;
    } else if (g == 1) {
      float di = dinv[n0 + 1];
      uint4 o;
      o.x = ((unsigned int)f2h(y1 * di) << 16) | (unsigned int)f2h(y0 * di);
      o.y = ((unsigned int)f2h(y3 * di) << 16) | (unsigned int)f2h(y2 * di);
      o.z = ((unsigned int)f2h(y5 * di) << 16) | (unsigned int)f2h(y4 * di);
      o.w = ((unsigned int)f2h(y7 * di) << 16) | (unsigned int)f2h(y6 * di);
      ((uint4*)(nm + (size_t)(n0 + 1) * 128))[c] = o;
    }
  }
}

// ---------------- MFMA GEMM (f16): OUT = act([A0|A1] @ WT^T + B) ----------------
template <int NOUT, bool RELU, bool OUT_F16>
__global__ __launch_bounds__(256, 4) void k_mm(
    const unsigned short* __restrict__ A0, const unsigned short* __restrict__ A1,
    const unsigned short* __restrict__ WT, const float* __restrict__ Bv,
    void* __restrict__ OUT) {
  constexpr int NFC = NOUT / 64;  // col-frags per wave
  __shared__ __align__(16) unsigned short sm[16896];  // 33792 B
  const int row0 = blockIdx.x * 64;
  const int tid = threadIdx.x;

  for (int i = tid; i < 1024; i += 256) {
    int r = i >> 4, c = i & 15;
    int gr = row0 + r;
    if (gr >= N_NODES) gr = N_NODES - 1;
    *(uint4*)(sm + r * 264 + c * 8) = ((const uint4*)(A0 + (size_t)gr * 128))[c];
    *(uint4*)(sm + r * 264 + 128 + c * 8) = ((const uint4*)(A1 + (size_t)gr * 128))[c];
  }

  const int lane = tid & 63;
  const int w = tid >> 6;
  const int r16 = lane & 15;
  const int kg = lane >> 4;
  const int wc0 = w * (NOUT / 4);

  f32x4 acc[4][NFC];
#pragma unroll
  for (int rf = 0; rf < 4; rf++)
#pragma unroll
    for (int cf = 0; cf < NFC; cf++) acc[rf][cf] = (f32x4){0.f, 0.f, 0.f, 0.f};

  __syncthreads();

  const unsigned short* wtb = WT + (size_t)(wc0 + r16) * 256 + kg * 8;
  const unsigned short* asb = sm + r16 * 264 + kg * 8;

  for (int ks = 0; ks < 8; ks++) {
    f16x8 a[4];
#pragma unroll
    for (int rf = 0; rf < 4; rf++)
      a[rf] = *(const f16x8*)(asb + rf * 16 * 264 + ks * 32);
#pragma unroll
    for (int cf = 0; cf < NFC; cf++) {
      f16x8 b = *(const f16x8*)(wtb + cf * 16 * 256 + ks * 32);
#pragma unroll
      for (int rf = 0; rf < 4; rf++)
        acc[rf][cf] = __builtin_amdgcn_mfma_f32_16x16x32_f16(a[rf], b, acc[rf][cf], 0, 0, 0);
    }
  }

  __syncthreads();  // reuse sm for output staging

  if (OUT_F16) {
    constexpr int LSO = NOUT + 8;
    unsigned short* so = sm;
#pragma unroll
    for (int rf = 0; rf < 4; rf++)
#pragma unroll
      for (int cf = 0; cf < NFC; cf++) {
        int col = wc0 + cf * 16 + r16;
        float bias = Bv[col];
#pragma unroll
        for (int r = 0; r < 4; r++) {
          int row = rf * 16 + kg * 4 + r;
          float v = acc[rf][cf][r] + bias;
          if (RELU) v = fmaxf(v, 0.f);
          so[row * LSO + col] = f2h(v);
        }
      }
    __syncthreads();
    unsigned short* O = (unsigned short*)OUT;
    for (int i = tid; i < 64 * (NOUT / 8); i += 256) {
      int r = i / (NOUT / 8), c = i % (NOUT / 8);
      int gr = row0 + r;
      if (gr < N_NODES)
        *(uint4*)(O + (size_t)gr * NOUT + c * 8) = *(const uint4*)(so + r * LSO + c * 8);
    }
  } else {
    constexpr int LSO = NOUT + 4;
    float* so = (float*)sm;
#pragma unroll
    for (int rf = 0; rf < 4; rf++)
#pragma unroll
      for (int cf = 0; cf < NFC; cf++) {
        int col = wc0 + cf * 16 + r16;
        float bias = Bv[col];
#pragma unroll
        for (int r = 0; r < 4; r++) {
          int row = rf * 16 + kg * 4 + r;
          float v = acc[rf][cf][r] + bias;
          if (RELU) v = fmaxf(v, 0.f);
          so[row * LSO + col] = v;
        }
      }
    __syncthreads();
    float* O = (float*)OUT;
    for (int i = tid; i < 64 * (NOUT / 4); i += 256) {
      int r = i / (NOUT / 4), c = i % (NOUT / 4);
      int gr = row0 + r;
      if (gr < N_NODES)
        *(float4*)(O + (size_t)gr * NOUT + c * 4) = *(const float4*)(so + r * LSO + c * 4);
    }
  }
}

// ---------------- launch ----------------

extern "C" void kernel_launch(void* const* d_in, const int* in_sizes, int n_in,
                              void* d_out, int out_size, void* d_ws, size_t ws_size,
                              hipStream_t stream) {
  const float* x   = (const float*)d_in[0];
  const int*   src = (const int*)d_in[1];
  const int*   dst = (const int*)d_in[2];
  const float* ws0 = (const float*)d_in[3];
  const float* wn0 = (const float*)d_in[4];
  const float* b0  = (const float*)d_in[5];
  const float* ws1 = (const float*)d_in[6];
  const float* wn1 = (const float*)d_in[7];
  const float* b1  = (const float*)d_in[8];
  const float* ws2 = (const float*)d_in[9];
  const float* wn2 = (const float*)d_in[10];
  const float* b2  = (const float*)d_in[11];
  float* out = (float*)d_out;

  uint8_t* base = (uint8_t*)d_ws;
  size_t off = 0;
  auto alloc = [&](size_t bytes) -> void* {
    void* p = base + off;
    off = (off + bytes + 255) & ~(size_t)255;
    return p;
  };
  int*   row_off = (int*)alloc((size_t)(N_NODES + 1) * 4);
  float* dinv    = (float*)alloc((size_t)N_NODES * 4);
  int*   csr     = (int*)alloc((size_t)N_EDGES * 4);
  unsigned int* stage = (unsigned int*)alloc((size_t)N_EDGES * 4);
  int*   bcount  = (int*)alloc((size_t)NB * 4);
  int*   boff    = (int*)alloc((size_t)(NB + 1) * 4);
  int*   bcursor = (int*)alloc((size_t)NB * 4);
  unsigned short* xb  = (unsigned short*)alloc((size_t)N_NODES * 128 * 2);
  unsigned short* nmb = (unsigned short*)alloc((size_t)N_NODES * 128 * 2);
  unsigned short* h1b = (unsigned short*)alloc((size_t)N_NODES * 128 * 2);
  unsigned short* h2b = (unsigned short*)alloc((size_t)N_NODES * 128 * 2);
  unsigned short* wt0 = (unsigned short*)alloc(128 * 256 * 2);
  unsigned short* wt1 = (unsigned short*)alloc(128 * 256 * 2);
  unsigned short* wt2 = (unsigned short*)alloc(64 * 256 * 2);

  hipMemsetAsync(bcount, 0, (size_t)NB * 4, stream);
  k_hist<<<(N_EDGES + 4095) / 4096, 256, 0, stream>>>(dst, bcount);
  k_bscan<<<1, 1024, 0, stream>>>(bcount, boff, bcursor);
  k_scatter<<<(N_EDGES + EPB - 1) / EPB, 256, 0, stream>>>(src, dst, bcursor, stage);
  k_bucket<<<NB, 256, 0, stream>>>(stage, boff, csr, row_off, dinv);

  k_cast<<<(N_NODES * 16 + 255) / 256, 256, 0, stream>>>(x, xb);
  k_wprep<<<64, 256, 0, stream>>>(ws0, wn0, 128, wt0);
  k_wprep<<<64, 256, 0, stream>>>(ws1, wn1, 128, wt1);
  k_wprep<<<32, 256, 0, stream>>>(ws2, wn2, 64, wt2);

  const int GMM = (N_NODES + 63) / 64;  // 1563

  // layer 0
  k_agg<<<AGG_BLOCKS, 256, 0, stream>>>(xb, row_off, csr, dinv, nmb);
  k_mm<128, true, true><<<GMM, 256, 0, stream>>>(xb, nmb, wt0, b0, h1b);
  // layer 1
  k_agg<<<AGG_BLOCKS, 256, 0, stream>>>(h1b, row_off, csr, dinv, nmb);
  k_mm<128, true, true><<<GMM, 256, 0, stream>>>(h1b, nmb, wt1, b1, h2b);
  // layer 2
  k_agg<<<AGG_BLOCKS, 256, 0, stream>>>(h2b, row_off, csr, dinv, nmb);
  k_mm<64, false, false><<<GMM, 256, 0, stream>>>(h2b, nmb, wt2, b2, out);
}

// Round 9
// 266.120 us; speedup vs baseline: 1.2707x; 1.2707x over previous
//
#include <hip/hip_runtime.h>
#include <stdint.h>

#define N_NODES 100000
#define N_EDGES 1000000
#define NB 782  // ceil(N_NODES/128) buckets of 128 nodes

typedef __attribute__((ext_vector_type(2))) _Float16 f16x2;
typedef __attribute__((ext_vector_type(8))) _Float16 f16x8;
typedef __attribute__((ext_vector_type(4))) float f32x4;

__device__ __forceinline__ unsigned short f2h(float f) {
  _Float16 h = (_Float16)f;
  return *(unsigned short*)&h;
}

// ---------------- bucketed CSR build ----------------

__global__ void k_hist(const int* __restrict__ dst, int* __restrict__ bcount) {
  __shared__ int h[NB];
  int t = threadIdx.x;
  for (int i = t; i < NB; i += 256) h[i] = 0;
  __syncthreads();
  int base = blockIdx.x * 4096;
#pragma unroll
  for (int k = 0; k < 16; k++) {
    int i = base + t + k * 256;
    if (i < N_EDGES) atomicAdd(&h[dst[i] >> 7], 1);
  }
  __syncthreads();
  for (int i = t; i < NB; i += 256)
    if (h[i]) atomicAdd(&bcount[i], h[i]);
}

__global__ __launch_bounds__(1024) void k_bscan(const int* __restrict__ bcount,
                                                int* __restrict__ boff,
                                                int* __restrict__ bcursor) {
  __shared__ int sc[1024];
  int t = threadIdx.x;
  int v = (t < NB) ? bcount[t] : 0;
  sc[t] = v;
  __syncthreads();
  for (int off = 1; off < 1024; off <<= 1) {
    int a = (t >= off) ? sc[t - off] : 0;
    __syncthreads();
    sc[t] += a;
    __syncthreads();
  }
  if (t < NB) {
    boff[t + 1] = sc[t];
    bcursor[t] = sc[t] - v;
  }
  if (t == 0) boff[0] = 0;
}

#define EPB 4096  // edges per scatter block -> 245 workgroups
__global__ void k_scatter(const int* __restrict__ src, const int* __restrict__ dst,
                          int* __restrict__ bcursor, unsigned int* __restrict__ stage) {
  __shared__ int h[NB];
  __shared__ int cur[NB];
  int t = threadIdx.x;
  for (int i = t; i < NB; i += 256) h[i] = 0;
  __syncthreads();
  int base = blockIdx.x * EPB;
#pragma unroll 4
  for (int k = 0; k < EPB / 256; k++) {
    int i = base + t + k * 256;
    if (i < N_EDGES) atomicAdd(&h[dst[i] >> 7], 1);
  }
  __syncthreads();
  for (int i = t; i < NB; i += 256) {
    int c = h[i];
    cur[i] = c ? atomicAdd(&bcursor[i], c) : 0;
  }
  __syncthreads();
#pragma unroll 4
  for (int k = 0; k < EPB / 256; k++) {
    int i = base + t + k * 256;
    if (i < N_EDGES) {
      int d = dst[i];
      int b = d >> 7;
      int pos = atomicAdd(&cur[b], 1);
      stage[pos] = ((unsigned int)(d & 127) << 17) | (unsigned int)src[i];
    }
  }
}

__global__ void k_bucket(const unsigned int* __restrict__ stage, const int* __restrict__ boff,
                         int* __restrict__ csr, int* __restrict__ row_off,
                         float* __restrict__ dinv) {
  __shared__ int cnt[128], sc[128], cur[128];
  int b = blockIdx.x, t = threadIdx.x;
  int e0 = boff[b], e1 = boff[b + 1];
  if (t < 128) cnt[t] = 0;
  __syncthreads();
  for (int e = e0 + t; e < e1; e += 256)
    atomicAdd(&cnt[stage[e] >> 17], 1);
  __syncthreads();
  int myc = (t < 128) ? cnt[t] : 0;
  if (t < 128) sc[t] = myc;
  __syncthreads();
  for (int off = 1; off < 128; off <<= 1) {
    int a = (t < 128 && t >= off) ? sc[t - off] : 0;
    __syncthreads();
    if (t < 128) sc[t] += a;
    __syncthreads();
  }
  if (t < 128) {
    int node = b * 128 + t;
    int ex = sc[t] - myc;
    cur[t] = ex;
    if (node < N_NODES) {
      row_off[node] = e0 + ex;
      dinv[node] = myc ? 1.0f / (float)myc : 0.0f;
    }
  }
  if (b == NB - 1 && t == 0) row_off[N_NODES] = N_EDGES;
  __syncthreads();
  for (int e = e0 + t; e < e1; e += 256) {
    unsigned int v = stage[e];
    int l = v >> 17;
    int pos = e0 + atomicAdd(&cur[l], 1);
    csr[pos] = (int)(v & 0x1FFFFu);
  }
}

// ---------------- fp32 -> f16 cast (x) ----------------
__global__ void k_cast(const float* __restrict__ x, unsigned short* __restrict__ xb) {
  int i = blockIdx.x * 256 + threadIdx.x;
  if (i >= N_NODES * 16) return;
  float4 a = ((const float4*)x)[2 * i];
  float4 b = ((const float4*)x)[2 * i + 1];
  unsigned short r[8] = {f2h(a.x), f2h(a.y), f2h(a.z), f2h(a.w),
                         f2h(b.x), f2h(b.y), f2h(b.z), f2h(b.w)};
  *(uint4*)(xb + (size_t)i * 8) = *(uint4*)r;
}

// ---------------- weight prep: f16, transposed + K-concat ----------------
__global__ void k_wprep(const float* __restrict__ WS, const float* __restrict__ WN,
                        int nout, unsigned short* __restrict__ wt) {
  int t = blockIdx.x * 256 + threadIdx.x;
  if (t >= nout * 128) return;
  int n = t >> 7, k = t & 127;
  wt[n * 256 + k] = f2h(WS[(size_t)k * nout + n]);
  wt[n * 256 + 128 + k] = f2h(WN[(size_t)k * nout + n]);
}

// ---------------- aggregation: wave/node, 16 slots, packed-f16 accumulate ----------------
// one wave per node (25000 blocks x 4 waves): max TLP wins for this
// latency-bound gather (R8 lesson: 2-node persistent waves regressed 42->67us)
__global__ void k_agg(const unsigned short* __restrict__ feat,
                      const int* __restrict__ row_off, const int* __restrict__ csr,
                      const float* __restrict__ dinv, unsigned short* __restrict__ nm) {
  int wv = threadIdx.x >> 6, lane = threadIdx.x & 63;
  int node = blockIdx.x * 4 + wv;
  if (node >= N_NODES) return;
  const uint4* fp = (const uint4*)feat;  // 16 uint4 per feature row
  int s0 = row_off[node], s1 = row_off[node + 1];
  int g = lane >> 4, c = lane & 15;
  f16x2 q0 = {0, 0}, q1 = {0, 0}, q2 = {0, 0}, q3 = {0, 0};
  for (int j = s0 + g; j < s1; j += 16) {
    int i1 = j + 4, i2 = j + 8, i3 = j + 12;
    bool h1 = i1 < s1, h2 = i2 < s1, h3 = i3 < s1;
    int c0 = csr[j];
    int c1 = h1 ? csr[i1] : 0;
    int c2 = h2 ? csr[i2] : 0;
    int c3 = h3 ? csr[i3] : 0;
    uint4 v0, v1, v2, v3;
    v0 = fp[(size_t)c0 * 16 + c];
    if (h1) v1 = fp[(size_t)c1 * 16 + c];
    if (h2) v2 = fp[(size_t)c2 * 16 + c];
    if (h3) v3 = fp[(size_t)c3 * 16 + c];
    q0 += *(const f16x2*)&v0.x; q1 += *(const f16x2*)&v0.y;
    q2 += *(const f16x2*)&v0.z; q3 += *(const f16x2*)&v0.w;
    if (h1) {
      q0 += *(const f16x2*)&v1.x; q1 += *(const f16x2*)&v1.y;
      q2 += *(const f16x2*)&v1.z; q3 += *(const f16x2*)&v1.w;
    }
    if (h2) {
      q0 += *(const f16x2*)&v2.x; q1 += *(const f16x2*)&v2.y;
      q2 += *(const f16x2*)&v2.z; q3 += *(const f16x2*)&v2.w;
    }
    if (h3) {
      q0 += *(const f16x2*)&v3.x; q1 += *(const f16x2*)&v3.y;
      q2 += *(const f16x2*)&v3.z; q3 += *(const f16x2*)&v3.w;
    }
  }
  float a0 = (float)q0[0], a1 = (float)q0[1], a2 = (float)q1[0], a3 = (float)q1[1];
  float a4 = (float)q2[0], a5 = (float)q2[1], a6 = (float)q3[0], a7 = (float)q3[1];
#define RED(x) x += __shfl_xor(x, 16); x += __shfl_xor(x, 32);
  RED(a0) RED(a1) RED(a2) RED(a3) RED(a4) RED(a5) RED(a6) RED(a7)
#undef RED
  if (g == 0) {
    float di = dinv[node];
    uint4 o;
    o.x = ((unsigned int)f2h(a1 * di) << 16) | (unsigned int)f2h(a0 * di);
    o.y = ((unsigned int)f2h(a3 * di) << 16) | (unsigned int)f2h(a2 * di);
    o.z = ((unsigned int)f2h(a5 * di) << 16) | (unsigned int)f2h(a4 * di);
    o.w = ((unsigned int)f2h(a7 * di) << 16) | (unsigned int)f2h(a6 * di);
    ((uint4*)(nm + (size_t)node * 128))[c] = o;
  }
}

// ---------------- MFMA GEMM (f16): OUT = act([A0|A1] @ WT^T + B) ----------------
template <int NOUT, bool RELU, bool OUT_F16>
__global__ __launch_bounds__(256, 4) void k_mm(
    const unsigned short* __restrict__ A0, const unsigned short* __restrict__ A1,
    const unsigned short* __restrict__ WT, const float* __restrict__ Bv,
    void* __restrict__ OUT) {
  constexpr int NFC = NOUT / 64;  // col-frags per wave
  __shared__ __align__(16) unsigned short sm[16896];  // 33792 B
  const int row0 = blockIdx.x * 64;
  const int tid = threadIdx.x;

  for (int i = tid; i < 1024; i += 256) {
    int r = i >> 4, c = i & 15;
    int gr = row0 + r;
    if (gr >= N_NODES) gr = N_NODES - 1;
    *(uint4*)(sm + r * 264 + c * 8) = ((const uint4*)(A0 + (size_t)gr * 128))[c];
    *(uint4*)(sm + r * 264 + 128 + c * 8) = ((const uint4*)(A1 + (size_t)gr * 128))[c];
  }

  const int lane = tid & 63;
  const int w = tid >> 6;
  const int r16 = lane & 15;
  const int kg = lane >> 4;
  const int wc0 = w * (NOUT / 4);

  f32x4 acc[4][NFC];
#pragma unroll
  for (int rf = 0; rf < 4; rf++)
#pragma unroll
    for (int cf = 0; cf < NFC; cf++) acc[rf][cf] = (f32x4){0.f, 0.f, 0.f, 0.f};

  __syncthreads();

  const unsigned short* wtb = WT + (size_t)(wc0 + r16) * 256 + kg * 8;
  const unsigned short* asb = sm + r16 * 264 + kg * 8;

  for (int ks = 0; ks < 8; ks++) {
    f16x8 a[4];
#pragma unroll
    for (int rf = 0; rf < 4; rf++)
      a[rf] = *(const f16x8*)(asb + rf * 16 * 264 + ks * 32);
#pragma unroll
    for (int cf = 0; cf < NFC; cf++) {
      f16x8 b = *(const f16x8*)(wtb + cf * 16 * 256 + ks * 32);
#pragma unroll
      for (int rf = 0; rf < 4; rf++)
        acc[rf][cf] = __builtin_amdgcn_mfma_f32_16x16x32_f16(a[rf], b, acc[rf][cf], 0, 0, 0);
    }
  }

  __syncthreads();  // reuse sm for output staging

  if (OUT_F16) {
    constexpr int LSO = NOUT + 8;
    unsigned short* so = sm;
#pragma unroll
    for (int rf = 0; rf < 4; rf++)
#pragma unroll
      for (int cf = 0; cf < NFC; cf++) {
        int col = wc0 + cf * 16 + r16;
        float bias = Bv[col];
#pragma unroll
        for (int r = 0; r < 4; r++) {
          int row = rf * 16 + kg * 4 + r;
          float v = acc[rf][cf][r] + bias;
          if (RELU) v = fmaxf(v, 0.f);
          so[row * LSO + col] = f2h(v);
        }
      }
    __syncthreads();
    unsigned short* O = (unsigned short*)OUT;
    for (int i = tid; i < 64 * (NOUT / 8); i += 256) {
      int r = i / (NOUT / 8), c = i % (NOUT / 8);
      int gr = row0 + r;
      if (gr < N_NODES)
        *(uint4*)(O + (size_t)gr * NOUT + c * 8) = *(const uint4*)(so + r * LSO + c * 8);
    }
  } else {
    constexpr int LSO = NOUT + 4;
    float* so = (float*)sm;
#pragma unroll
    for (int rf = 0; rf < 4; rf++)
#pragma unroll
      for (int cf = 0; cf < NFC; cf++) {
        int col = wc0 + cf * 16 + r16;
        float bias = Bv[col];
#pragma unroll
        for (int r = 0; r < 4; r++) {
          int row = rf * 16 + kg * 4 + r;
          float v = acc[rf][cf][r] + bias;
          if (RELU) v = fmaxf(v, 0.f);
          so[row * LSO + col] = v;
        }
      }
    __syncthreads();
    float* O = (float*)OUT;
    for (int i = tid; i < 64 * (NOUT / 4); i += 256) {
      int r = i / (NOUT / 4), c = i % (NOUT / 4);
      int gr = row0 + r;
      if (gr < N_NODES)
        *(float4*)(O + (size_t)gr * NOUT + c * 4) = *(const float4*)(so + r * LSO + c * 4);
    }
  }
}

// ---------------- launch ----------------

extern "C" void kernel_launch(void* const* d_in, const int* in_sizes, int n_in,
                              void* d_out, int out_size, void* d_ws, size_t ws_size,
                              hipStream_t stream) {
  const float* x   = (const float*)d_in[0];
  const int*   src = (const int*)d_in[1];
  const int*   dst = (const int*)d_in[2];
  const float* ws0 = (const float*)d_in[3];
  const float* wn0 = (const float*)d_in[4];
  const float* b0  = (const float*)d_in[5];
  const float* ws1 = (const float*)d_in[6];
  const float* wn1 = (const float*)d_in[7];
  const float* b1  = (const float*)d_in[8];
  const float* ws2 = (const float*)d_in[9];
  const float* wn2 = (const float*)d_in[10];
  const float* b2  = (const float*)d_in[11];
  float* out = (float*)d_out;

  uint8_t* base = (uint8_t*)d_ws;
  size_t off = 0;
  auto alloc = [&](size_t bytes) -> void* {
    void* p = base + off;
    off = (off + bytes + 255) & ~(size_t)255;
    return p;
  };
  int*   row_off = (int*)alloc((size_t)(N_NODES + 1) * 4);
  float* dinv    = (float*)alloc((size_t)N_NODES * 4);
  int*   csr     = (int*)alloc((size_t)N_EDGES * 4);
  unsigned int* stage = (unsigned int*)alloc((size_t)N_EDGES * 4);
  int*   bcount  = (int*)alloc((size_t)NB * 4);
  int*   boff    = (int*)alloc((size_t)(NB + 1) * 4);
  int*   bcursor = (int*)alloc((size_t)NB * 4);
  unsigned short* xb  = (unsigned short*)alloc((size_t)N_NODES * 128 * 2);
  unsigned short* nmb = (unsigned short*)alloc((size_t)N_NODES * 128 * 2);
  unsigned short* h1b = (unsigned short*)alloc((size_t)N_NODES * 128 * 2);
  unsigned short* h2b = (unsigned short*)alloc((size_t)N_NODES * 128 * 2);
  unsigned short* wt0 = (unsigned short*)alloc(128 * 256 * 2);
  unsigned short* wt1 = (unsigned short*)alloc(128 * 256 * 2);
  unsigned short* wt2 = (unsigned short*)alloc(64 * 256 * 2);

  hipMemsetAsync(bcount, 0, (size_t)NB * 4, stream);
  k_hist<<<(N_EDGES + 4095) / 4096, 256, 0, stream>>>(dst, bcount);
  k_bscan<<<1, 1024, 0, stream>>>(bcount, boff, bcursor);
  k_scatter<<<(N_EDGES + EPB - 1) / EPB, 256, 0, stream>>>(src, dst, bcursor, stage);
  k_bucket<<<NB, 256, 0, stream>>>(stage, boff, csr, row_off, dinv);

  k_cast<<<(N_NODES * 16 + 255) / 256, 256, 0, stream>>>(x, xb);
  k_wprep<<<64, 256, 0, stream>>>(ws0, wn0, 128, wt0);
  k_wprep<<<64, 256, 0, stream>>>(ws1, wn1, 128, wt1);
  k_wprep<<<32, 256, 0, stream>>>(ws2, wn2, 64, wt2);

  const int GMM = (N_NODES + 63) / 64;  // 1563

  // layer 0
  k_agg<<<25000, 256, 0, stream>>>(xb, row_off, csr, dinv, nmb);
  k_mm<128, true, true><<<GMM, 256, 0, stream>>>(xb, nmb, wt0, b0, h1b);
  // layer 1
  k_agg<<<25000, 256, 0, stream>>>(h1b, row_off, csr, dinv, nmb);
  k_mm<128, true, true><<<GMM, 256, 0, stream>>>(h1b, nmb, wt1, b1, h2b);
  // layer 2
  k_agg<<<25000, 256, 0, stream>>>(h2b, row_off, csr, dinv, nmb);
  k_mm<64, false, false><<<GMM, 256, 0, stream>>>(h2b, nmb, wt2, b2, out);
}

// Round 10
// 255.721 us; speedup vs baseline: 1.3224x; 1.0407x over previous
//
#include <hip/hip_runtime.h>
#include <stdint.h>

#define N_NODES 100000
#define N_EDGES 1000000
#define NB 782   // ceil(N_NODES/128) buckets of 128 nodes
#define CAP 4096 // stage arena slots per bucket (expected ~1280 +- 36)
#define EPB 2048 // edges per scatter block -> 489 workgroups

typedef __attribute__((ext_vector_type(2))) _Float16 f16x2;
typedef __attribute__((ext_vector_type(8))) _Float16 f16x8;
typedef __attribute__((ext_vector_type(4))) float f32x4;

__device__ __forceinline__ unsigned short f2h(float f) {
  _Float16 h = (_Float16)f;
  return *(unsigned short*)&h;
}

// ---------------- one-pass bucketed scatter into chunked arena ----------------
// bcnt[b] must be zeroed before launch; after: bcnt[b] = bucket edge count.
__global__ void k_scatter(const int* __restrict__ src, const int* __restrict__ dst,
                          int* __restrict__ bcnt, unsigned int* __restrict__ stage) {
  __shared__ int h[NB];
  __shared__ int cur[NB];
  int t = threadIdx.x;
  for (int i = t; i < NB; i += 256) h[i] = 0;
  __syncthreads();
  int base = blockIdx.x * EPB;
#pragma unroll 8
  for (int k = 0; k < EPB / 256; k++) {
    int i = base + t + k * 256;
    if (i < N_EDGES) atomicAdd(&h[dst[i] >> 7], 1);
  }
  __syncthreads();
  for (int i = t; i < NB; i += 256) {
    int c = h[i];
    cur[i] = c ? atomicAdd(&bcnt[i], c) : 0;
  }
  __syncthreads();
#pragma unroll 8
  for (int k = 0; k < EPB / 256; k++) {
    int i = base + t + k * 256;
    if (i < N_EDGES) {
      int d = dst[i];
      int b = d >> 7;
      int pos = atomicAdd(&cur[b], 1);
      stage[(size_t)b * CAP + pos] = ((unsigned int)(d & 127) << 17) | (unsigned int)src[i];
    }
  }
}

// exclusive scan of bucket counts -> boff[0..NB]
__global__ __launch_bounds__(1024) void k_bscan(const int* __restrict__ bcnt,
                                                int* __restrict__ boff) {
  __shared__ int sc[1024];
  int t = threadIdx.x;
  int v = (t < NB) ? bcnt[t] : 0;
  sc[t] = v;
  __syncthreads();
  for (int off = 1; off < 1024; off <<= 1) {
    int a = (t >= off) ? sc[t - off] : 0;
    __syncthreads();
    sc[t] += a;
    __syncthreads();
  }
  if (t < NB) boff[t + 1] = sc[t];
  if (t == 0) boff[0] = 0;
}

// per-bucket: node counts + local scan -> row_off/dinv, compact csr
__global__ void k_bucket(const unsigned int* __restrict__ stage, const int* __restrict__ boff,
                         int* __restrict__ csr, int* __restrict__ row_off,
                         float* __restrict__ dinv) {
  __shared__ int cnt[128], sc[128], cur[128];
  int b = blockIdx.x, t = threadIdx.x;
  int e0 = boff[b];
  int nb = boff[b + 1] - e0;
  const unsigned int* sb = stage + (size_t)b * CAP;
  if (t < 128) cnt[t] = 0;
  __syncthreads();
  for (int e = t; e < nb; e += 256)
    atomicAdd(&cnt[sb[e] >> 17], 1);
  __syncthreads();
  int myc = (t < 128) ? cnt[t] : 0;
  if (t < 128) sc[t] = myc;
  __syncthreads();
  for (int off = 1; off < 128; off <<= 1) {
    int a = (t < 128 && t >= off) ? sc[t - off] : 0;
    __syncthreads();
    if (t < 128) sc[t] += a;
    __syncthreads();
  }
  if (t < 128) {
    int node = b * 128 + t;
    int ex = sc[t] - myc;
    cur[t] = ex;
    if (node < N_NODES) {
      row_off[node] = e0 + ex;
      dinv[node] = myc ? 1.0f / (float)myc : 0.0f;
    }
  }
  if (b == NB - 1 && t == 0) row_off[N_NODES] = N_EDGES;
  __syncthreads();
  for (int e = t; e < nb; e += 256) {
    unsigned int v = sb[e];
    int l = v >> 17;
    int pos = e0 + atomicAdd(&cur[l], 1);
    csr[pos] = (int)(v & 0x1FFFFu);
  }
}

// ---------------- fused prep: fp32->f16 cast of x + 3x weight transpose ----------------
// blocks [0,6250): cast (6250*256 = 1.6M = N_NODES*16 exactly)
// blocks [6250,6314): wt0   [6314,6378): wt1   [6378,6410): wt2
__global__ void k_prep(const float* __restrict__ x, unsigned short* __restrict__ xb,
                       const float* __restrict__ ws0, const float* __restrict__ wn0,
                       unsigned short* __restrict__ wt0,
                       const float* __restrict__ ws1, const float* __restrict__ wn1,
                       unsigned short* __restrict__ wt1,
                       const float* __restrict__ ws2, const float* __restrict__ wn2,
                       unsigned short* __restrict__ wt2) {
  int b = blockIdx.x;
  if (b < 6250) {
    int i = b * 256 + threadIdx.x;
    float4 a = ((const float4*)x)[2 * i];
    float4 v = ((const float4*)x)[2 * i + 1];
    unsigned short r[8] = {f2h(a.x), f2h(a.y), f2h(a.z), f2h(a.w),
                           f2h(v.x), f2h(v.y), f2h(v.z), f2h(v.w)};
    *(uint4*)(xb + (size_t)i * 8) = *(uint4*)r;
    return;
  }
  int t = (b - 6250) * 256 + threadIdx.x;  // 0 .. 40959
  const float* WS; const float* WN; unsigned short* WT; int nout;
  if (t < 16384) { WS = ws0; WN = wn0; WT = wt0; nout = 128; }
  else if (t < 32768) { t -= 16384; WS = ws1; WN = wn1; WT = wt1; nout = 128; }
  else { t -= 32768; if (t >= 8192) return; WS = ws2; WN = wn2; WT = wt2; nout = 64; }
  int n = t >> 7, k = t & 127;
  WT[n * 256 + k] = f2h(WS[(size_t)k * nout + n]);
  WT[n * 256 + 128 + k] = f2h(WN[(size_t)k * nout + n]);
}

// ---------------- aggregation: wave/node, 16 slots, packed-f16 accumulate ----------------
// one wave per node (25000 blocks x 4 waves): max TLP wins for this
// latency-bound gather (R8 lesson: 2-node persistent waves regressed 42->67us)
__global__ void k_agg(const unsigned short* __restrict__ feat,
                      const int* __restrict__ row_off, const int* __restrict__ csr,
                      const float* __restrict__ dinv, unsigned short* __restrict__ nm) {
  int wv = threadIdx.x >> 6, lane = threadIdx.x & 63;
  int node = blockIdx.x * 4 + wv;
  if (node >= N_NODES) return;
  const uint4* fp = (const uint4*)feat;  // 16 uint4 per feature row
  int s0 = row_off[node], s1 = row_off[node + 1];
  int g = lane >> 4, c = lane & 15;
  f16x2 q0 = {0, 0}, q1 = {0, 0}, q2 = {0, 0}, q3 = {0, 0};
  for (int j = s0 + g; j < s1; j += 16) {
    int i1 = j + 4, i2 = j + 8, i3 = j + 12;
    bool h1 = i1 < s1, h2 = i2 < s1, h3 = i3 < s1;
    int c0 = csr[j];
    int c1 = h1 ? csr[i1] : 0;
    int c2 = h2 ? csr[i2] : 0;
    int c3 = h3 ? csr[i3] : 0;
    uint4 v0, v1, v2, v3;
    v0 = fp[(size_t)c0 * 16 + c];
    if (h1) v1 = fp[(size_t)c1 * 16 + c];
    if (h2) v2 = fp[(size_t)c2 * 16 + c];
    if (h3) v3 = fp[(size_t)c3 * 16 + c];
    q0 += *(const f16x2*)&v0.x; q1 += *(const f16x2*)&v0.y;
    q2 += *(const f16x2*)&v0.z; q3 += *(const f16x2*)&v0.w;
    if (h1) {
      q0 += *(const f16x2*)&v1.x; q1 += *(const f16x2*)&v1.y;
      q2 += *(const f16x2*)&v1.z; q3 += *(const f16x2*)&v1.w;
    }
    if (h2) {
      q0 += *(const f16x2*)&v2.x; q1 += *(const f16x2*)&v2.y;
      q2 += *(const f16x2*)&v2.z; q3 += *(const f16x2*)&v2.w;
    }
    if (h3) {
      q0 += *(const f16x2*)&v3.x; q1 += *(const f16x2*)&v3.y;
      q2 += *(const f16x2*)&v3.z; q3 += *(const f16x2*)&v3.w;
    }
  }
  float a0 = (float)q0[0], a1 = (float)q0[1], a2 = (float)q1[0], a3 = (float)q1[1];
  float a4 = (float)q2[0], a5 = (float)q2[1], a6 = (float)q3[0], a7 = (float)q3[1];
#define RED(x) x += __shfl_xor(x, 16); x += __shfl_xor(x, 32);
  RED(a0) RED(a1) RED(a2) RED(a3) RED(a4) RED(a5) RED(a6) RED(a7)
#undef RED
  if (g == 0) {
    float di = dinv[node];
    uint4 o;
    o.x = ((unsigned int)f2h(a1 * di) << 16) | (unsigned int)f2h(a0 * di);
    o.y = ((unsigned int)f2h(a3 * di) << 16) | (unsigned int)f2h(a2 * di);
    o.z = ((unsigned int)f2h(a5 * di) << 16) | (unsigned int)f2h(a4 * di);
    o.w = ((unsigned int)f2h(a7 * di) << 16) | (unsigned int)f2h(a6 * di);
    ((uint4*)(nm + (size_t)node * 128))[c] = o;
  }
}

// ---------------- MFMA GEMM (f16): OUT = act([A0|A1] @ WT^T + B) ----------------
template <int NOUT, bool RELU, bool OUT_F16>
__global__ __launch_bounds__(256, 4) void k_mm(
    const unsigned short* __restrict__ A0, const unsigned short* __restrict__ A1,
    const unsigned short* __restrict__ WT, const float* __restrict__ Bv,
    void* __restrict__ OUT) {
  constexpr int NFC = NOUT / 64;  // col-frags per wave
  __shared__ __align__(16) unsigned short sm[16896];  // 33792 B
  const int row0 = blockIdx.x * 64;
  const int tid = threadIdx.x;

  for (int i = tid; i < 1024; i += 256) {
    int r = i >> 4, c = i & 15;
    int gr = row0 + r;
    if (gr >= N_NODES) gr = N_NODES - 1;
    *(uint4*)(sm + r * 264 + c * 8) = ((const uint4*)(A0 + (size_t)gr * 128))[c];
    *(uint4*)(sm + r * 264 + 128 + c * 8) = ((const uint4*)(A1 + (size_t)gr * 128))[c];
  }

  const int lane = tid & 63;
  const int w = tid >> 6;
  const int r16 = lane & 15;
  const int kg = lane >> 4;
  const int wc0 = w * (NOUT / 4);

  f32x4 acc[4][NFC];
#pragma unroll
  for (int rf = 0; rf < 4; rf++)
#pragma unroll
    for (int cf = 0; cf < NFC; cf++) acc[rf][cf] = (f32x4){0.f, 0.f, 0.f, 0.f};

  __syncthreads();

  const unsigned short* wtb = WT + (size_t)(wc0 + r16) * 256 + kg * 8;
  const unsigned short* asb = sm + r16 * 264 + kg * 8;

  for (int ks = 0; ks < 8; ks++) {
    f16x8 a[4];
#pragma unroll
    for (int rf = 0; rf < 4; rf++)
      a[rf] = *(const f16x8*)(asb + rf * 16 * 264 + ks * 32);
#pragma unroll
    for (int cf = 0; cf < NFC; cf++) {
      f16x8 b = *(const f16x8*)(wtb + cf * 16 * 256 + ks * 32);
#pragma unroll
      for (int rf = 0; rf < 4; rf++)
        acc[rf][cf] = __builtin_amdgcn_mfma_f32_16x16x32_f16(a[rf], b, acc[rf][cf], 0, 0, 0);
    }
  }

  __syncthreads();  // reuse sm for output staging

  if (OUT_F16) {
    constexpr int LSO = NOUT + 8;
    unsigned short* so = sm;
#pragma unroll
    for (int rf = 0; rf < 4; rf++)
#pragma unroll
      for (int cf = 0; cf < NFC; cf++) {
        int col = wc0 + cf * 16 + r16;
        float bias = Bv[col];
#pragma unroll
        for (int r = 0; r < 4; r++) {
          int row = rf * 16 + kg * 4 + r;
          float v = acc[rf][cf][r] + bias;
          if (RELU) v = fmaxf(v, 0.f);
          so[row * LSO + col] = f2h(v);
        }
      }
    __syncthreads();
    unsigned short* O = (unsigned short*)OUT;
    for (int i = tid; i < 64 * (NOUT / 8); i += 256) {
      int r = i / (NOUT / 8), c = i % (NOUT / 8);
      int gr = row0 + r;
      if (gr < N_NODES)
        *(uint4*)(O + (size_t)gr * NOUT + c * 8) = *(const uint4*)(so + r * LSO + c * 8);
    }
  } else {
    constexpr int LSO = NOUT + 4;
    float* so = (float*)sm;
#pragma unroll
    for (int rf = 0; rf < 4; rf++)
#pragma unroll
      for (int cf = 0; cf < NFC; cf++) {
        int col = wc0 + cf * 16 + r16;
        float bias = Bv[col];
#pragma unroll
        for (int r = 0; r < 4; r++) {
          int row = rf * 16 + kg * 4 + r;
          float v = acc[rf][cf][r] + bias;
          if (RELU) v = fmaxf(v, 0.f);
          so[row * LSO + col] = v;
        }
      }
    __syncthreads();
    float* O = (float*)OUT;
    for (int i = tid; i < 64 * (NOUT / 4); i += 256) {
      int r = i / (NOUT / 4), c = i % (NOUT / 4);
      int gr = row0 + r;
      if (gr < N_NODES)
        *(float4*)(O + (size_t)gr * NOUT + c * 4) = *(const float4*)(so + r * LSO + c * 4);
    }
  }
}

// ---------------- launch ----------------

extern "C" void kernel_launch(void* const* d_in, const int* in_sizes, int n_in,
                              void* d_out, int out_size, void* d_ws, size_t ws_size,
                              hipStream_t stream) {
  const float* x   = (const float*)d_in[0];
  const int*   src = (const int*)d_in[1];
  const int*   dst = (const int*)d_in[2];
  const float* ws0 = (const float*)d_in[3];
  const float* wn0 = (const float*)d_in[4];
  const float* b0  = (const float*)d_in[5];
  const float* ws1 = (const float*)d_in[6];
  const float* wn1 = (const float*)d_in[7];
  const float* b1  = (const float*)d_in[8];
  const float* ws2 = (const float*)d_in[9];
  const float* wn2 = (const float*)d_in[10];
  const float* b2  = (const float*)d_in[11];
  float* out = (float*)d_out;

  uint8_t* base = (uint8_t*)d_ws;
  size_t off = 0;
  auto alloc = [&](size_t bytes) -> void* {
    void* p = base + off;
    off = (off + bytes + 255) & ~(size_t)255;
    return p;
  };
  int*   row_off = (int*)alloc((size_t)(N_NODES + 1) * 4);
  float* dinv    = (float*)alloc((size_t)N_NODES * 4);
  int*   csr     = (int*)alloc((size_t)N_EDGES * 4);
  unsigned int* stage = (unsigned int*)alloc((size_t)NB * CAP * 4);  // 12.8 MB arena
  int*   bcnt    = (int*)alloc((size_t)NB * 4);
  int*   boff    = (int*)alloc((size_t)(NB + 1) * 4);
  unsigned short* xb  = (unsigned short*)alloc((size_t)N_NODES * 128 * 2);
  unsigned short* nmb = (unsigned short*)alloc((size_t)N_NODES * 128 * 2);
  unsigned short* h1b = (unsigned short*)alloc((size_t)N_NODES * 128 * 2);
  unsigned short* h2b = (unsigned short*)alloc((size_t)N_NODES * 128 * 2);
  unsigned short* wt0 = (unsigned short*)alloc(128 * 256 * 2);
  unsigned short* wt1 = (unsigned short*)alloc(128 * 256 * 2);
  unsigned short* wt2 = (unsigned short*)alloc(64 * 256 * 2);

  hipMemsetAsync(bcnt, 0, (size_t)NB * 4, stream);
  k_scatter<<<(N_EDGES + EPB - 1) / EPB, 256, 0, stream>>>(src, dst, bcnt, stage);
  k_bscan<<<1, 1024, 0, stream>>>(bcnt, boff);
  k_bucket<<<NB, 256, 0, stream>>>(stage, boff, csr, row_off, dinv);

  k_prep<<<6410, 256, 0, stream>>>(x, xb, ws0, wn0, wt0, ws1, wn1, wt1, ws2, wn2, wt2);

  const int GMM = (N_NODES + 63) / 64;  // 1563

  // layer 0
  k_agg<<<25000, 256, 0, stream>>>(xb, row_off, csr, dinv, nmb);
  k_mm<128, true, true><<<GMM, 256, 0, stream>>>(xb, nmb, wt0, b0, h1b);
  // layer 1
  k_agg<<<25000, 256, 0, stream>>>(h1b, row_off, csr, dinv, nmb);
  k_mm<128, true, true><<<GMM, 256, 0, stream>>>(h1b, nmb, wt1, b1, h2b);
  // layer 2
  k_agg<<<25000, 256, 0, stream>>>(h2b, row_off, csr, dinv, nmb);
  k_mm<64, false, false><<<GMM, 256, 0, stream>>>(h2b, nmb, wt2, b2, out);
}

// Round 11
// 246.928 us; speedup vs baseline: 1.3695x; 1.0356x over previous
//
#include <hip/hip_runtime.h>
#include <stdint.h>

#define N_NODES 100000
#define N_EDGES 1000000
#define NB 782   // ceil(N_NODES/128) buckets of 128 nodes
#define CAP 4096 // arena slots per bucket (expected ~1280 +- 36)
#define EPB 2048 // edges per scatter block -> 489 scatter blocks
#define SCB ((N_EDGES + EPB - 1) / EPB)  // 489
#define PREPB 6410  // 6250 cast blocks + 160 weight blocks

typedef __attribute__((ext_vector_type(2))) _Float16 f16x2;
typedef __attribute__((ext_vector_type(8))) _Float16 f16x8;
typedef __attribute__((ext_vector_type(4))) float f32x4;

__device__ __forceinline__ unsigned short f2h(float f) {
  _Float16 h = (_Float16)f;
  return *(unsigned short*)&h;
}

// ---------------- fused: bucketed scatter (blocks 0..SCB) + prep (rest) ----------------
// scatter: one-pass into chunked arena; bcnt[b] pre-zeroed, ends as bucket count.
// prep: fp32->f16 cast of x + 3x weight transpose/concat (independent work that
// co-resides with the latency-bound scatter blocks to fill the machine).
__global__ void k_scatter_prep(const int* __restrict__ src, const int* __restrict__ dst,
                               int* __restrict__ bcnt, unsigned int* __restrict__ stage,
                               const float* __restrict__ x, unsigned short* __restrict__ xb,
                               const float* __restrict__ ws0, const float* __restrict__ wn0,
                               unsigned short* __restrict__ wt0,
                               const float* __restrict__ ws1, const float* __restrict__ wn1,
                               unsigned short* __restrict__ wt1,
                               const float* __restrict__ ws2, const float* __restrict__ wn2,
                               unsigned short* __restrict__ wt2) {
  __shared__ int h[NB];
  __shared__ int cur[NB];
  int t = threadIdx.x;
  if (blockIdx.x < SCB) {
    for (int i = t; i < NB; i += 256) h[i] = 0;
    __syncthreads();
    int base = blockIdx.x * EPB;
#pragma unroll 8
    for (int k = 0; k < EPB / 256; k++) {
      int i = base + t + k * 256;
      if (i < N_EDGES) atomicAdd(&h[dst[i] >> 7], 1);
    }
    __syncthreads();
    for (int i = t; i < NB; i += 256) {
      int c = h[i];
      cur[i] = c ? atomicAdd(&bcnt[i], c) : 0;
    }
    __syncthreads();
#pragma unroll 8
    for (int k = 0; k < EPB / 256; k++) {
      int i = base + t + k * 256;
      if (i < N_EDGES) {
        int d = dst[i];
        int b = d >> 7;
        int pos = atomicAdd(&cur[b], 1);
        stage[(size_t)b * CAP + pos] = ((unsigned int)(d & 127) << 17) | (unsigned int)src[i];
      }
    }
    return;
  }
  int b = blockIdx.x - SCB;
  if (b < 6250) {
    int i = b * 256 + t;  // 6250*256 == N_NODES*16 exactly
    float4 a = ((const float4*)x)[2 * i];
    float4 v = ((const float4*)x)[2 * i + 1];
    unsigned short r[8] = {f2h(a.x), f2h(a.y), f2h(a.z), f2h(a.w),
                           f2h(v.x), f2h(v.y), f2h(v.z), f2h(v.w)};
    *(uint4*)(xb + (size_t)i * 8) = *(uint4*)r;
    return;
  }
  int w = (b - 6250) * 256 + t;  // 0 .. 40959
  const float* WS; const float* WN; unsigned short* WT; int nout;
  if (w < 16384) { WS = ws0; WN = wn0; WT = wt0; nout = 128; }
  else if (w < 32768) { w -= 16384; WS = ws1; WN = wn1; WT = wt1; nout = 128; }
  else { w -= 32768; if (w >= 8192) return; WS = ws2; WN = wn2; WT = wt2; nout = 64; }
  int n = w >> 7, k = w & 127;
  WT[n * 256 + k] = f2h(WS[(size_t)k * nout + n]);
  WT[n * 256 + 128 + k] = f2h(WN[(size_t)k * nout + n]);
}

// ---------------- per-bucket: group by node within arena chunk (no global scan) ----------------
// csr stays arena-chunked: node lists live at [b*CAP + local_excl_scan).
__global__ void k_bucket(const unsigned int* __restrict__ stage, const int* __restrict__ bcnt,
                         int* __restrict__ csr, int* __restrict__ rowbeg,
                         int* __restrict__ rowend, float* __restrict__ dinv) {
  __shared__ int cnt[128], sc[128], cur[128];
  int b = blockIdx.x, t = threadIdx.x;
  int nb = bcnt[b];
  const unsigned int* sb = stage + (size_t)b * CAP;
  int e0 = b * CAP;
  if (t < 128) cnt[t] = 0;
  __syncthreads();
  for (int e = t; e < nb; e += 256)
    atomicAdd(&cnt[sb[e] >> 17], 1);
  __syncthreads();
  int myc = (t < 128) ? cnt[t] : 0;
  if (t < 128) sc[t] = myc;
  __syncthreads();
  for (int off = 1; off < 128; off <<= 1) {
    int a = (t < 128 && t >= off) ? sc[t - off] : 0;
    __syncthreads();
    if (t < 128) sc[t] += a;
    __syncthreads();
  }
  if (t < 128) {
    int node = b * 128 + t;
    int ex = sc[t] - myc;
    cur[t] = ex;
    if (node < N_NODES) {
      rowbeg[node] = e0 + ex;
      rowend[node] = e0 + ex + myc;
      dinv[node] = myc ? 1.0f / (float)myc : 0.0f;
    }
  }
  __syncthreads();
  for (int e = t; e < nb; e += 256) {
    unsigned int v = sb[e];
    int l = v >> 17;
    int pos = e0 + atomicAdd(&cur[l], 1);
    csr[pos] = (int)(v & 0x1FFFFu);
  }
}

// ---------------- aggregation: wave/node, 16 slots, packed-f16 accumulate ----------------
// one wave per node (25000 blocks x 4 waves): max TLP wins for this
// latency-bound gather (R8 lesson: 2-node persistent waves regressed 42->67us)
__global__ void k_agg(const unsigned short* __restrict__ feat,
                      const int* __restrict__ rowbeg, const int* __restrict__ rowend,
                      const int* __restrict__ csr,
                      const float* __restrict__ dinv, unsigned short* __restrict__ nm) {
  int wv = threadIdx.x >> 6, lane = threadIdx.x & 63;
  int node = blockIdx.x * 4 + wv;
  if (node >= N_NODES) return;
  const uint4* fp = (const uint4*)feat;  // 16 uint4 per feature row
  int s0 = rowbeg[node], s1 = rowend[node];
  int g = lane >> 4, c = lane & 15;
  f16x2 q0 = {0, 0}, q1 = {0, 0}, q2 = {0, 0}, q3 = {0, 0};
  for (int j = s0 + g; j < s1; j += 16) {
    int i1 = j + 4, i2 = j + 8, i3 = j + 12;
    bool h1 = i1 < s1, h2 = i2 < s1, h3 = i3 < s1;
    int c0 = csr[j];
    int c1 = h1 ? csr[i1] : 0;
    int c2 = h2 ? csr[i2] : 0;
    int c3 = h3 ? csr[i3] : 0;
    uint4 v0, v1, v2, v3;
    v0 = fp[(size_t)c0 * 16 + c];
    if (h1) v1 = fp[(size_t)c1 * 16 + c];
    if (h2) v2 = fp[(size_t)c2 * 16 + c];
    if (h3) v3 = fp[(size_t)c3 * 16 + c];
    q0 += *(const f16x2*)&v0.x; q1 += *(const f16x2*)&v0.y;
    q2 += *(const f16x2*)&v0.z; q3 += *(const f16x2*)&v0.w;
    if (h1) {
      q0 += *(const f16x2*)&v1.x; q1 += *(const f16x2*)&v1.y;
      q2 += *(const f16x2*)&v1.z; q3 += *(const f16x2*)&v1.w;
    }
    if (h2) {
      q0 += *(const f16x2*)&v2.x; q1 += *(const f16x2*)&v2.y;
      q2 += *(const f16x2*)&v2.z; q3 += *(const f16x2*)&v2.w;
    }
    if (h3) {
      q0 += *(const f16x2*)&v3.x; q1 += *(const f16x2*)&v3.y;
      q2 += *(const f16x2*)&v3.z; q3 += *(const f16x2*)&v3.w;
    }
  }
  float a0 = (float)q0[0], a1 = (float)q0[1], a2 = (float)q1[0], a3 = (float)q1[1];
  float a4 = (float)q2[0], a5 = (float)q2[1], a6 = (float)q3[0], a7 = (float)q3[1];
#define RED(x) x += __shfl_xor(x, 16); x += __shfl_xor(x, 32);
  RED(a0) RED(a1) RED(a2) RED(a3) RED(a4) RED(a5) RED(a6) RED(a7)
#undef RED
  if (g == 0) {
    float di = dinv[node];
    uint4 o;
    o.x = ((unsigned int)f2h(a1 * di) << 16) | (unsigned int)f2h(a0 * di);
    o.y = ((unsigned int)f2h(a3 * di) << 16) | (unsigned int)f2h(a2 * di);
    o.z = ((unsigned int)f2h(a5 * di) << 16) | (unsigned int)f2h(a4 * di);
    o.w = ((unsigned int)f2h(a7 * di) << 16) | (unsigned int)f2h(a6 * di);
    ((uint4*)(nm + (size_t)node * 128))[c] = o;
  }
}

// ---------------- MFMA GEMM (f16): OUT = act([A0|A1] @ WT^T + B) ----------------
template <int NOUT, bool RELU, bool OUT_F16>
__global__ __launch_bounds__(256, 4) void k_mm(
    const unsigned short* __restrict__ A0, const unsigned short* __restrict__ A1,
    const unsigned short* __restrict__ WT, const float* __restrict__ Bv,
    void* __restrict__ OUT) {
  constexpr int NFC = NOUT / 64;  // col-frags per wave
  __shared__ __align__(16) unsigned short sm[16896];  // 33792 B
  const int row0 = blockIdx.x * 64;
  const int tid = threadIdx.x;

  for (int i = tid; i < 1024; i += 256) {
    int r = i >> 4, c = i & 15;
    int gr = row0 + r;
    if (gr >= N_NODES) gr = N_NODES - 1;
    *(uint4*)(sm + r * 264 + c * 8) = ((const uint4*)(A0 + (size_t)gr * 128))[c];
    *(uint4*)(sm + r * 264 + 128 + c * 8) = ((const uint4*)(A1 + (size_t)gr * 128))[c];
  }

  const int lane = tid & 63;
  const int w = tid >> 6;
  const int r16 = lane & 15;
  const int kg = lane >> 4;
  const int wc0 = w * (NOUT / 4);

  f32x4 acc[4][NFC];
#pragma unroll
  for (int rf = 0; rf < 4; rf++)
#pragma unroll
    for (int cf = 0; cf < NFC; cf++) acc[rf][cf] = (f32x4){0.f, 0.f, 0.f, 0.f};

  __syncthreads();

  const unsigned short* wtb = WT + (size_t)(wc0 + r16) * 256 + kg * 8;
  const unsigned short* asb = sm + r16 * 264 + kg * 8;

  for (int ks = 0; ks < 8; ks++) {
    f16x8 a[4];
#pragma unroll
    for (int rf = 0; rf < 4; rf++)
      a[rf] = *(const f16x8*)(asb + rf * 16 * 264 + ks * 32);
#pragma unroll
    for (int cf = 0; cf < NFC; cf++) {
      f16x8 b = *(const f16x8*)(wtb + cf * 16 * 256 + ks * 32);
#pragma unroll
      for (int rf = 0; rf < 4; rf++)
        acc[rf][cf] = __builtin_amdgcn_mfma_f32_16x16x32_f16(a[rf], b, acc[rf][cf], 0, 0, 0);
    }
  }

  __syncthreads();  // reuse sm for output staging

  if (OUT_F16) {
    constexpr int LSO = NOUT + 8;
    unsigned short* so = sm;
#pragma unroll
    for (int rf = 0; rf < 4; rf++)
#pragma unroll
      for (int cf = 0; cf < NFC; cf++) {
        int col = wc0 + cf * 16 + r16;
        float bias = Bv[col];
#pragma unroll
        for (int r = 0; r < 4; r++) {
          int row = rf * 16 + kg * 4 + r;
          float v = acc[rf][cf][r] + bias;
          if (RELU) v = fmaxf(v, 0.f);
          so[row * LSO + col] = f2h(v);
        }
      }
    __syncthreads();
    unsigned short* O = (unsigned short*)OUT;
    for (int i = tid; i < 64 * (NOUT / 8); i += 256) {
      int r = i / (NOUT / 8), c = i % (NOUT / 8);
      int gr = row0 + r;
      if (gr < N_NODES)
        *(uint4*)(O + (size_t)gr * NOUT + c * 8) = *(const uint4*)(so + r * LSO + c * 8);
    }
  } else {
    constexpr int LSO = NOUT + 4;
    float* so = (float*)sm;
#pragma unroll
    for (int rf = 0; rf < 4; rf++)
#pragma unroll
      for (int cf = 0; cf < NFC; cf++) {
        int col = wc0 + cf * 16 + r16;
        float bias = Bv[col];
#pragma unroll
        for (int r = 0; r < 4; r++) {
          int row = rf * 16 + kg * 4 + r;
          float v = acc[rf][cf][r] + bias;
          if (RELU) v = fmaxf(v, 0.f);
          so[row * LSO + col] = v;
        }
      }
    __syncthreads();
    float* O = (float*)OUT;
    for (int i = tid; i < 64 * (NOUT / 4); i += 256) {
      int r = i / (NOUT / 4), c = i % (NOUT / 4);
      int gr = row0 + r;
      if (gr < N_NODES)
        *(float4*)(O + (size_t)gr * NOUT + c * 4) = *(const float4*)(so + r * LSO + c * 4);
    }
  }
}

// ---------------- launch ----------------

extern "C" void kernel_launch(void* const* d_in, const int* in_sizes, int n_in,
                              void* d_out, int out_size, void* d_ws, size_t ws_size,
                              hipStream_t stream) {
  const float* x   = (const float*)d_in[0];
  const int*   src = (const int*)d_in[1];
  const int*   dst = (const int*)d_in[2];
  const float* ws0 = (const float*)d_in[3];
  const float* wn0 = (const float*)d_in[4];
  const float* b0  = (const float*)d_in[5];
  const float* ws1 = (const float*)d_in[6];
  const float* wn1 = (const float*)d_in[7];
  const float* b1  = (const float*)d_in[8];
  const float* ws2 = (const float*)d_in[9];
  const float* wn2 = (const float*)d_in[10];
  const float* b2  = (const float*)d_in[11];
  float* out = (float*)d_out;

  uint8_t* base = (uint8_t*)d_ws;
  size_t off = 0;
  auto alloc = [&](size_t bytes) -> void* {
    void* p = base + off;
    off = (off + bytes + 255) & ~(size_t)255;
    return p;
  };
  int*   rowbeg  = (int*)alloc((size_t)N_NODES * 4);
  int*   rowend  = (int*)alloc((size_t)N_NODES * 4);
  float* dinv    = (float*)alloc((size_t)N_NODES * 4);
  int*   csr     = (int*)alloc((size_t)NB * CAP * 4);       // 12.8 MB arena
  unsigned int* stage = (unsigned int*)alloc((size_t)NB * CAP * 4);  // 12.8 MB arena
  int*   bcnt    = (int*)alloc((size_t)NB * 4);
  unsigned short* xb  = (unsigned short*)alloc((size_t)N_NODES * 128 * 2);
  unsigned short* nmb = (unsigned short*)alloc((size_t)N_NODES * 128 * 2);
  unsigned short* h1b = (unsigned short*)alloc((size_t)N_NODES * 128 * 2);
  unsigned short* h2b = (unsigned short*)alloc((size_t)N_NODES * 128 * 2);
  unsigned short* wt0 = (unsigned short*)alloc(128 * 256 * 2);
  unsigned short* wt1 = (unsigned short*)alloc(128 * 256 * 2);
  unsigned short* wt2 = (unsigned short*)alloc(64 * 256 * 2);

  hipMemsetAsync(bcnt, 0, (size_t)NB * 4, stream);
  k_scatter_prep<<<SCB + PREPB, 256, 0, stream>>>(src, dst, bcnt, stage,
                                                  x, xb, ws0, wn0, wt0,
                                                  ws1, wn1, wt1, ws2, wn2, wt2);
  k_bucket<<<NB, 256, 0, stream>>>(stage, bcnt, csr, rowbeg, rowend, dinv);

  const int GMM = (N_NODES + 63) / 64;  // 1563

  // layer 0
  k_agg<<<25000, 256, 0, stream>>>(xb, rowbeg, rowend, csr, dinv, nmb);
  k_mm<128, true, true><<<GMM, 256, 0, stream>>>(xb, nmb, wt0, b0, h1b);
  // layer 1
  k_agg<<<25000, 256, 0, stream>>>(h1b, rowbeg, rowend, csr, dinv, nmb);
  k_mm<128, true, true><<<GMM, 256, 0, stream>>>(h1b, nmb, wt1, b1, h2b);
  // layer 2
  k_agg<<<25000, 256, 0, stream>>>(h2b, rowbeg, rowend, csr, dinv, nmb);
  k_mm<64, false, false><<<GMM, 256, 0, stream>>>(h2b, nmb, wt2, b2, out);
}